// Round 8
// baseline (670.895 us; speedup 1.0000x reference)
//
#include <hip/hip_runtime.h>
#include <stdint.h>

// VQ argmin, bit-replicating numpy fp32 reference (see R2).
// R8: R7's 16x8 tile + DMA dbuf + atomic merge, with launch_bounds(256,2):
// R7's (256,1) collapsed occupancy to 1 block/CU (10.75%) and exposed all
// LDS/barrier latency. (256,2) caps VGPR at 256 (>=184 needed, no spill)
// and restores 2 blocks/CU. Model: LDS 9216 vs VALU 8192 cyc/phase ->
// ~89% VALUBusy, vq ~140-155us.
// B=16 D=256 H=W=32 -> n=16384 pixels; K=2048 codes.

#define D_    256
#define K_    2048
#define HW_   1024
#define MT    128     // pixels per block
#define NT    256     // codes per acc chunk
#define KT    16      // dims per phase
#define SPLIT 4
#define KS    (K_ / SPLIT)   // 512 codes per block
#define CST   260     // cs row stride: 16B-aligned rows, 2-way banks (free)
#define ZSZ   (KT * MT)            // 2048 floats
#define BUFSZ (ZSZ + KT * CST)     // 6208 floats per buffer
#define NPIX  16384

// global -> LDS direct DMA, 16 B per lane, wave-uniform LDS base
__device__ __forceinline__ void gload16(const float* g, float* l) {
    auto* gp = reinterpret_cast<const __attribute__((address_space(1))) uint32_t*>(
        reinterpret_cast<uintptr_t>(g));
    auto* lp = reinterpret_cast<__attribute__((address_space(3))) uint32_t*>(
        reinterpret_cast<uintptr_t>(l));
    __builtin_amdgcn_global_load_lds(gp, lp, 16, 0, 0);
}

// numpy pairwise combine of 8 accumulators
__device__ __forceinline__ float pw8(const float r[8]) {
    float t01 = __fadd_rn(r[0], r[1]);
    float t23 = __fadd_rn(r[2], r[3]);
    float L   = __fadd_rn(t01, t23);
    float t45 = __fadd_rn(r[4], r[5]);
    float t67 = __fadd_rn(r[6], r[7]);
    float R   = __fadd_rn(t45, t67);
    return __fadd_rn(L, R);
}

// prep: [0,128) transpose cb->ct (+blk0 zeroes cnt); [128,136) Bn;
//       [136,200) An + keys init
__global__ __launch_bounds__(256) void prep_k(const float* __restrict__ z,
                                              const float* __restrict__ cb,
                                              float* __restrict__ ct,
                                              float* __restrict__ An,
                                              float* __restrict__ Bn,
                                              unsigned long long* __restrict__ keys,
                                              int* __restrict__ cnt) {
    __shared__ float t[64][65];
    int tid = threadIdx.x;
    int bx  = blockIdx.x;
    if (bx < 128) {
        if (bx == 0 && tid < MT) cnt[tid] = 0;
        int k0 = (bx & 31) << 6;
        int d0 = (bx >> 5) << 6;
        #pragma unroll
        for (int it = 0; it < 4; ++it) {
            int u  = (it << 8) + tid;
            int kk = u >> 4;
            int dd = (u & 15) << 2;
            float4 v = *reinterpret_cast<const float4*>(
                cb + (size_t)(k0 + kk) * D_ + d0 + dd);
            t[kk][dd + 0] = v.x; t[kk][dd + 1] = v.y;
            t[kk][dd + 2] = v.z; t[kk][dd + 3] = v.w;
        }
        __syncthreads();
        #pragma unroll
        for (int it = 0; it < 4; ++it) {
            int u  = (it << 8) + tid;
            int dd = u >> 4;
            int kk = (u & 15) << 2;
            float4 o;
            o.x = t[kk + 0][dd]; o.y = t[kk + 1][dd];
            o.z = t[kk + 2][dd]; o.w = t[kk + 3][dd];
            *reinterpret_cast<float4*>(ct + (size_t)(d0 + dd) * K_ + k0 + kk) = o;
        }
    } else if (bx < 136) {
        int row = (bx - 128) * 256 + tid;
        const float4* p = reinterpret_cast<const float4*>(cb + (size_t)row * D_);
        float rA[8], rB[8];
        #pragma unroll
        for (int j = 0; j < 8; ++j) { rA[j] = 0.f; rB[j] = 0.f; }
        #pragma unroll
        for (int q = 0; q < 64; ++q) {
            float4 v = p[q];
            float pv[4] = {__fmul_rn(v.x, v.x), __fmul_rn(v.y, v.y),
                           __fmul_rn(v.z, v.z), __fmul_rn(v.w, v.w)};
            if (q < 32) {
                #pragma unroll
                for (int l = 0; l < 4; ++l)
                    rA[(4 * q + l) & 7] = __fadd_rn(rA[(4 * q + l) & 7], pv[l]);
            } else {
                #pragma unroll
                for (int l = 0; l < 4; ++l)
                    rB[(4 * q + l) & 7] = __fadd_rn(rB[(4 * q + l) & 7], pv[l]);
            }
        }
        Bn[row] = __fadd_rn(pw8(rA), pw8(rB));
    } else {
        int blk = bx - 136;                  // [0,64): 256 pixels each
        int b   = blk >> 2;
        int hw0 = (blk & 3) << 8;
        keys[(size_t)b * HW_ + hw0 + tid] = 0xFFFFFFFFFFFFFFFFull;
        const float* zb = z + (size_t)b * (D_ * HW_) + hw0 + tid;
        float rA[8], rB[8];
        #pragma unroll
        for (int j = 0; j < 8; ++j) { rA[j] = 0.f; rB[j] = 0.f; }
        #pragma unroll 8
        for (int d = 0; d < 128; ++d) {
            float v = zb[(size_t)d * HW_];
            rA[d & 7] = __fadd_rn(rA[d & 7], __fmul_rn(v, v));
        }
        #pragma unroll 8
        for (int d = 128; d < 256; ++d) {
            float v = zb[(size_t)d * HW_];
            rB[d & 7] = __fadd_rn(rB[d & 7], __fmul_rn(v, v));
        }
        An[(size_t)b * HW_ + hw0 + tid] = __fadd_rn(pw8(rA), pw8(rB));
    }
}

// main GEMM+argmin: DMA double-buffer; 16x8 tile; atomicMin merge; fused gather
__global__ __launch_bounds__(256, 2) void vq_k(const float* __restrict__ z,
                                               const float* __restrict__ ct,
                                               const float* __restrict__ cb,
                                               const float* __restrict__ An,
                                               const float* __restrict__ Bn,
                                               unsigned long long* __restrict__ keys,
                                               int* __restrict__ cnt,
                                               float* __restrict__ out) {
    __shared__ float smem[2 * BUFSZ];            // 49664 B
    __shared__ int sflag;
    float* rs = smem;                            // [128][33] aliased for reduce
    int*   ri = (int*)(smem + MT * 33);
    int*   idxs = ri;                            // reused for gather

    const int tid  = threadIdx.x;
    const int lane = tid & 63;
    const int w    = tid >> 6;                   // wave id [0,4)
    const int tn   = (tid & 7) | (w << 3);       // [0,32); 8 values per wave
    const int tm   = (tid >> 3) & 7;             // [0,8)
    const int blk  = blockIdx.x;
    const int p    = blk >> 2;                   // pixel-block [0,128)
    const int s    = blk & 3;                    // K-split slice
    const int b      = p >> 3;
    const int hwbase = (p & 7) << 7;             // 128 pixels
    const float* zbase = z + (size_t)b * (D_ * HW_) + hwbase;
    const float* ctS   = ct + s * KS;

    // per-lane DMA source offsets
    const float* zsrc = zbase + (size_t)(lane >> 5) * HW_ + ((lane & 31) << 2);
    const float* csrc = ctS + ((size_t)lane << 2);

    float bs[16]; int bi[16];
    #pragma unroll
    for (int i = 0; i < 16; ++i) { bs[i] = 1e30f; bi[i] = 0; }
    float acc[16][8];
    #pragma unroll
    for (int i = 0; i < 16; ++i)
        #pragma unroll
        for (int j = 0; j < 8; ++j) acc[i][j] = 0.f;

    // stage phase ph into buf[ph&1]: wave w covers dims 4w..4w+3 of the phase
    #define STAGE(ph)                                                         \
        do {                                                                  \
            int buf_ = (ph) & 1, kc_ = (ph) & 15, nc_ = (ph) >> 4;            \
            float* zb_ = smem + buf_ * BUFSZ;                                 \
            float* cb_ = zb_ + ZSZ;                                           \
            _Pragma("unroll")                                                 \
            for (int t = 0; t < 2; ++t) {                                     \
                int row = (w << 2) + (t << 1);                                \
                gload16(zsrc + (size_t)(kc_ * KT + row) * HW_,                \
                        zb_ + row * MT);                                      \
            }                                                                 \
            _Pragma("unroll")                                                 \
            for (int r = 0; r < 4; ++r) {                                     \
                int row = (w << 2) + r;                                       \
                gload16(csrc + (size_t)(kc_ * KT + row) * K_ + nc_ * NT,      \
                        cb_ + row * CST);                                     \
            }                                                                 \
        } while (0)

    STAGE(0);

    for (int ph = 0; ph < 32; ++ph) {
        __syncthreads();              // drains phase-ph DMA (issued 1 phase ago)
        if (ph < 31) STAGE(ph + 1);   // other buffer; hidden behind FMA below
        const float* zb_ = smem + (ph & 1) * BUFSZ;
        const float* cb_ = zb_ + ZSZ;
        // ascending-k single-acc FMA chain — bit-matches sgemm
        #pragma unroll
        for (int d = 0; d < KT; ++d) {
            const float* zr = zb_ + d * MT + (tm << 3);
            float4 a0 = *reinterpret_cast<const float4*>(zr);
            float4 a1 = *reinterpret_cast<const float4*>(zr + 4);
            float4 a2 = *reinterpret_cast<const float4*>(zr + 64);
            float4 a3 = *reinterpret_cast<const float4*>(zr + 68);
            const float* cr = cb_ + d * CST + (tn << 3);
            float4 b0 = *reinterpret_cast<const float4*>(cr);
            float4 b1 = *reinterpret_cast<const float4*>(cr + 4);
            float av[16] = {a0.x, a0.y, a0.z, a0.w, a1.x, a1.y, a1.z, a1.w,
                            a2.x, a2.y, a2.z, a2.w, a3.x, a3.y, a3.z, a3.w};
            float bv[8]  = {b0.x, b0.y, b0.z, b0.w, b1.x, b1.y, b1.z, b1.w};
            #pragma unroll
            for (int i = 0; i < 16; ++i)
                #pragma unroll
                for (int j = 0; j < 8; ++j)
                    acc[i][j] = fmaf(av[i], bv[j], acc[i][j]);
        }
        if ((ph & 15) == 15) {
            int nc = ph >> 4;
            float an[16];
            #pragma unroll
            for (int i = 0; i < 16; ++i) {
                int m = (i < 8) ? ((tm << 3) + i) : (64 + (tm << 3) + i - 8);
                an[i] = An[(size_t)b * HW_ + hwbase + m];
            }
            #pragma unroll
            for (int j = 0; j < 8; ++j) {
                int ng = s * KS + nc * NT + (tn << 3) + j;
                float bn = Bn[ng];
                #pragma unroll
                for (int i = 0; i < 16; ++i) {
                    float sc = __fsub_rn(__fadd_rn(an[i], bn),
                                         __fmul_rn(2.0f, acc[i][j]));
                    if (sc < bs[i]) { bs[i] = sc; bi[i] = ng; }
                }
            }
            #pragma unroll
            for (int i = 0; i < 16; ++i)
                #pragma unroll
                for (int j = 0; j < 8; ++j) acc[i][j] = 0.f;
        }
    }
    #undef STAGE

    __syncthreads();   // done with smem buffers
    #pragma unroll
    for (int i = 0; i < 16; ++i) {
        int m = (i < 8) ? ((tm << 3) + i) : (64 + (tm << 3) + i - 8);
        rs[m * 33 + tn] = bs[i];
        ri[m * 33 + tn] = bi[i];
    }
    __syncthreads();
    unsigned long long* keyp = keys + (size_t)b * HW_ + hwbase;
    if (tid < MT) {
        float best = rs[tid * 33];
        int   bidx = ri[tid * 33];
        for (int t = 1; t < 32; ++t) {
            float sv = rs[tid * 33 + t];
            int   ix = ri[tid * 33 + t];
            if (sv < best || (sv == best && ix < bidx)) { best = sv; bidx = ix; }
        }
        // score > 0 always (||z||^2 ~ 256 dominates) -> fp32 bits order-preserving
        unsigned long long key =
            ((unsigned long long)__float_as_uint(best) << 32) | (unsigned)bidx;
        atomicMin(keyp + tid, key);
    }
    __threadfence();
    __syncthreads();
    if (tid == 0) sflag = atomicAdd(cnt + p, 1);
    __syncthreads();
    if (sflag == 3) {                 // last of 4 splits: gather + store
        if (tid < MT) {
            unsigned long long v = atomicMin(keyp + tid, 0xFFFFFFFFFFFFFFFFull);
            idxs[tid] = (int)(unsigned)v;
        }
        __syncthreads();
        float* obase = out + (size_t)b * (D_ * HW_) + hwbase;
        #pragma unroll
        for (int it = 0; it < 32; ++it) {
            int u  = (it << 8) + tid;
            int dd = u >> 5;          // [0,256)
            int c4 = u & 31;          // float4 column
            int i0 = idxs[(c4 << 2) + 0];
            int i1 = idxs[(c4 << 2) + 1];
            int i2 = idxs[(c4 << 2) + 2];
            int i3 = idxs[(c4 << 2) + 3];
            float4 o;
            o.x = cb[(size_t)i0 * D_ + dd];
            o.y = cb[(size_t)i1 * D_ + dd];
            o.z = cb[(size_t)i2 * D_ + dd];
            o.w = cb[(size_t)i3 * D_ + dd];
            *reinterpret_cast<float4*>(obase + (size_t)dd * HW_ + (c4 << 2)) = o;
        }
    }
}

extern "C" void kernel_launch(void* const* d_in, const int* in_sizes, int n_in,
                              void* d_out, int out_size, void* d_ws, size_t ws_size,
                              hipStream_t stream) {
    const float* z  = (const float*)d_in[0];   // 16*256*32*32
    const float* cb = (const float*)d_in[1];   // 2048*256
    unsigned long long* keys = (unsigned long long*)d_ws;   // 16384
    int*   cnt = (int*)(keys + NPIX);                       // 128
    float* An  = (float*)(cnt + MT);                        // 16384
    float* Bn  = An + NPIX;                                 // 2048
    float* ct  = Bn + K_;                                   // 256*2048 (2 MB)
    float* out = (float*)d_out;

    prep_k<<<dim3(200), dim3(256), 0, stream>>>(z, cb, ct, An, Bn, keys, cnt);
    vq_k<<<dim3(128 * SPLIT), dim3(256), 0, stream>>>(z, ct, cb, An, Bn,
                                                      keys, cnt, out);
}

// Round 9
// 343.127 us; speedup vs baseline: 1.9552x; 1.9552x over previous
//
#include <hip/hip_runtime.h>
#include <stdint.h>

// VQ argmin, bit-replicating numpy fp32 reference (see R2).
// R9: R6's proven 8x8 tile / DMA dbuf / (256,2) [VGPR cap 128, no spill],
// plus: (a) bank-quad swizzle — each b128's 8 wave-addresses cover all 32
// banks (R6 pattern used 16 banks -> 16.7 cyc/b128; swizzle -> ~8-12);
// (b) fin_k fused via atomicMin(u64 key) + last-finisher gather (R7-proven).
// Numerics identical: ascending-k fmaf chain; fold fsub(fadd,fmul); pairwise
// norms; first-min tie-break (explicit index clause in fold).
// B=16 D=256 H=W=32 -> n=16384 pixels; K=2048 codes.

#define D_    256
#define K_    2048
#define HW_   1024
#define MT    64      // pixels per block
#define NT    256     // codes per acc chunk
#define KT    16      // dims per phase
#define SPLIT 2
#define KS    (K_ / SPLIT)   // 1024 codes per block
#define CST   260     // cs row stride: 16B-aligned rows; 260%32=4 keeps quads valid
#define ZSZ   (KT * MT)
#define BUFSZ (ZSZ + KT * CST)   // 5184 floats per buffer
#define NPIX  16384

// global -> LDS direct DMA, 16 B per lane, wave-uniform LDS base
__device__ __forceinline__ void gload16(const float* g, float* l) {
    auto* gp = reinterpret_cast<const __attribute__((address_space(1))) uint32_t*>(
        reinterpret_cast<uintptr_t>(g));
    auto* lp = reinterpret_cast<__attribute__((address_space(3))) uint32_t*>(
        reinterpret_cast<uintptr_t>(l));
    __builtin_amdgcn_global_load_lds(gp, lp, 16, 0, 0);
}

// numpy pairwise combine of 8 accumulators
__device__ __forceinline__ float pw8(const float r[8]) {
    float t01 = __fadd_rn(r[0], r[1]);
    float t23 = __fadd_rn(r[2], r[3]);
    float L   = __fadd_rn(t01, t23);
    float t45 = __fadd_rn(r[4], r[5]);
    float t67 = __fadd_rn(r[6], r[7]);
    float R   = __fadd_rn(t45, t67);
    return __fadd_rn(L, R);
}

// prep: [0,128) transpose cb->ct (+blk0 zeroes cnt); [128,136) Bn;
//       [136,200) An + keys init
__global__ __launch_bounds__(256) void prep_k(const float* __restrict__ z,
                                              const float* __restrict__ cb,
                                              float* __restrict__ ct,
                                              float* __restrict__ An,
                                              float* __restrict__ Bn,
                                              unsigned long long* __restrict__ keys,
                                              int* __restrict__ cnt) {
    __shared__ float t[64][65];
    int tid = threadIdx.x;
    int bx  = blockIdx.x;
    if (bx < 128) {
        if (bx == 0) cnt[tid] = 0;           // 256 pixel-blocks
        int k0 = (bx & 31) << 6;
        int d0 = (bx >> 5) << 6;
        #pragma unroll
        for (int it = 0; it < 4; ++it) {
            int u  = (it << 8) + tid;
            int kk = u >> 4;
            int dd = (u & 15) << 2;
            float4 v = *reinterpret_cast<const float4*>(
                cb + (size_t)(k0 + kk) * D_ + d0 + dd);
            t[kk][dd + 0] = v.x; t[kk][dd + 1] = v.y;
            t[kk][dd + 2] = v.z; t[kk][dd + 3] = v.w;
        }
        __syncthreads();
        #pragma unroll
        for (int it = 0; it < 4; ++it) {
            int u  = (it << 8) + tid;
            int dd = u >> 4;
            int kk = (u & 15) << 2;
            float4 o;
            o.x = t[kk + 0][dd]; o.y = t[kk + 1][dd];
            o.z = t[kk + 2][dd]; o.w = t[kk + 3][dd];
            *reinterpret_cast<float4*>(ct + (size_t)(d0 + dd) * K_ + k0 + kk) = o;
        }
    } else if (bx < 136) {
        int row = (bx - 128) * 256 + tid;
        const float4* p = reinterpret_cast<const float4*>(cb + (size_t)row * D_);
        float rA[8], rB[8];
        #pragma unroll
        for (int j = 0; j < 8; ++j) { rA[j] = 0.f; rB[j] = 0.f; }
        #pragma unroll
        for (int q = 0; q < 64; ++q) {
            float4 v = p[q];
            float pv[4] = {__fmul_rn(v.x, v.x), __fmul_rn(v.y, v.y),
                           __fmul_rn(v.z, v.z), __fmul_rn(v.w, v.w)};
            if (q < 32) {
                #pragma unroll
                for (int l = 0; l < 4; ++l)
                    rA[(4 * q + l) & 7] = __fadd_rn(rA[(4 * q + l) & 7], pv[l]);
            } else {
                #pragma unroll
                for (int l = 0; l < 4; ++l)
                    rB[(4 * q + l) & 7] = __fadd_rn(rB[(4 * q + l) & 7], pv[l]);
            }
        }
        Bn[row] = __fadd_rn(pw8(rA), pw8(rB));
    } else {
        int blk = bx - 136;                  // [0,64): 256 pixels each
        int b   = blk >> 2;
        int hw0 = (blk & 3) << 8;
        keys[(size_t)b * HW_ + hw0 + tid] = 0xFFFFFFFFFFFFFFFFull;
        const float* zb = z + (size_t)b * (D_ * HW_) + hw0 + tid;
        float rA[8], rB[8];
        #pragma unroll
        for (int j = 0; j < 8; ++j) { rA[j] = 0.f; rB[j] = 0.f; }
        #pragma unroll 8
        for (int d = 0; d < 128; ++d) {
            float v = zb[(size_t)d * HW_];
            rA[d & 7] = __fadd_rn(rA[d & 7], __fmul_rn(v, v));
        }
        #pragma unroll 8
        for (int d = 128; d < 256; ++d) {
            float v = zb[(size_t)d * HW_];
            rB[d & 7] = __fadd_rn(rB[d & 7], __fmul_rn(v, v));
        }
        An[(size_t)b * HW_ + hw0 + tid] = __fadd_rn(pw8(rA), pw8(rB));
    }
}

// main GEMM+argmin: DMA dbuf; bank-quad-swizzled 8x8 tile; atomic merge+gather
__global__ __launch_bounds__(256, 2) void vq_k(const float* __restrict__ z,
                                               const float* __restrict__ ct,
                                               const float* __restrict__ cb,
                                               const float* __restrict__ An,
                                               const float* __restrict__ Bn,
                                               unsigned long long* __restrict__ keys,
                                               int* __restrict__ cnt,
                                               float* __restrict__ out) {
    __shared__ float smem[2 * BUFSZ];            // 41472 B
    __shared__ int sflag;
    float* rs = smem;                            // [64][33] aliased for reduce
    int*   ri = (int*)(smem + MT * 33);
    int*   idxs = ri;                            // reused for gather

    const int tid  = threadIdx.x;
    const int lane = tid & 63;
    const int w    = tid >> 6;                   // wave id [0,4)
    const int u    = tid & 7;                    // code-group within wave
    const int tm   = (tid >> 3) & 7;             // pixel-group within wave
    const int tn   = u | (w << 3);               // [0,32) reduce column
    const int blk  = blockIdx.x;
    const int p    = blk >> 1;                   // pixel-block [0,256)
    const int s    = blk & 1;                    // K-split slice
    const int b      = p >> 4;
    const int hwbase = (p & 15) << 6;
    const float* zbase = z + (size_t)b * (D_ * HW_) + hwbase;
    const float* ctS   = ct + s * KS;

    // bank-quad swizzle: two 4-elem quads per thread; per-instr the 8 wave
    // addresses hit 8 distinct bank-quads (cover all 32 banks).
    const int q1 = (u < 4) ? u : u + 8;          // {0,1,2,3,12,13,14,15}
    const int q2 = u + 4;                        // {4..11}
    const int p1 = (tm < 4) ? tm : tm + 8;
    const int p2 = tm + 4;
    const int co1 = (w << 6) + (q1 << 2);        // c float offsets (rel row)
    const int co2 = (w << 6) + (q2 << 2);
    const int zo1 = p1 << 2;                     // z float offsets (rel row)
    const int zo2 = p2 << 2;

    // per-lane DMA source offsets (dense staging, unchanged from R6)
    const float* zsrc = zbase + (size_t)((w << 2) + (lane >> 4)) * HW_
                              + ((lane & 15) << 2);
    const float* csrc = ctS + ((size_t)lane << 2);

    float bs[8]; int bi[8];
    #pragma unroll
    for (int i = 0; i < 8; ++i) { bs[i] = 1e30f; bi[i] = 0; }
    float acc[8][8];
    #pragma unroll
    for (int i = 0; i < 8; ++i)
        #pragma unroll
        for (int j = 0; j < 8; ++j) acc[i][j] = 0.f;

    #define STAGE(ph)                                                         \
        do {                                                                  \
            int buf_ = (ph) & 1, kc_ = (ph) & 15, nc_ = (ph) >> 4;            \
            float* zb_ = smem + buf_ * BUFSZ;                                 \
            float* cb_ = zb_ + ZSZ;                                           \
            gload16(zsrc + (size_t)kc_ * (KT * HW_), zb_ + (w << 2) * MT);    \
            _Pragma("unroll")                                                 \
            for (int r = 0; r < 4; ++r) {                                     \
                int row = (w << 2) + r;                                       \
                gload16(csrc + (size_t)((kc_ << 4) + row) * K_ + nc_ * NT,    \
                        cb_ + row * CST);                                     \
            }                                                                 \
        } while (0)

    STAGE(0);

    for (int ph = 0; ph < 64; ++ph) {
        __syncthreads();              // drains phase-ph DMA (issued 1 phase ago)
        if (ph < 63) STAGE(ph + 1);   // other buffer; hidden behind FMA below
        const float* zb_ = smem + (ph & 1) * BUFSZ;
        const float* cb_ = zb_ + ZSZ;
        // ascending-k single-acc FMA chain — bit-matches sgemm
        #pragma unroll
        for (int d = 0; d < KT; ++d) {
            const float* zr = zb_ + d * MT;
            float4 a0 = *reinterpret_cast<const float4*>(zr + zo1);
            float4 a1 = *reinterpret_cast<const float4*>(zr + zo2);
            const float* cr = cb_ + d * CST;
            float4 b0 = *reinterpret_cast<const float4*>(cr + co1);
            float4 b1 = *reinterpret_cast<const float4*>(cr + co2);
            float av[8] = {a0.x, a0.y, a0.z, a0.w, a1.x, a1.y, a1.z, a1.w};
            float bv[8] = {b0.x, b0.y, b0.z, b0.w, b1.x, b1.y, b1.z, b1.w};
            #pragma unroll
            for (int i = 0; i < 8; ++i)
                #pragma unroll
                for (int j = 0; j < 8; ++j)
                    acc[i][j] = fmaf(av[i], bv[j], acc[i][j]);
        }
        if ((ph & 15) == 15) {
            int nc = ph >> 4;
            #pragma unroll
            for (int j = 0; j < 8; ++j) {
                // code relabel per swizzle (non-monotonic j -> explicit tiebreak)
                int cc = (j < 4) ? ((q1 << 2) + j) : ((q2 << 2) + j - 4);
                int ng = s * KS + nc * NT + (w << 6) + cc;
                float bn = Bn[ng];
                #pragma unroll
                for (int i = 0; i < 8; ++i) {
                    int m = (i < 4) ? ((p1 << 2) + i) : ((p2 << 2) + i - 4);
                    float an = An[(size_t)b * HW_ + hwbase + m];
                    float sc = __fsub_rn(__fadd_rn(an, bn),
                                         __fmul_rn(2.0f, acc[i][j]));
                    if (sc < bs[i] || (sc == bs[i] && ng < bi[i])) {
                        bs[i] = sc; bi[i] = ng;
                    }
                }
            }
            #pragma unroll
            for (int i = 0; i < 8; ++i)
                #pragma unroll
                for (int j = 0; j < 8; ++j) acc[i][j] = 0.f;
        }
    }
    #undef STAGE

    __syncthreads();   // done with smem buffers
    #pragma unroll
    for (int i = 0; i < 8; ++i) {
        int m = (i < 4) ? ((p1 << 2) + i) : ((p2 << 2) + i - 4);
        rs[m * 33 + tn] = bs[i];
        ri[m * 33 + tn] = bi[i];
    }
    __syncthreads();
    unsigned long long* keyp = keys + (size_t)b * HW_ + hwbase;
    if (tid < MT) {
        float best = rs[tid * 33];
        int   bidx = ri[tid * 33];
        for (int t = 1; t < 32; ++t) {
            float sv = rs[tid * 33 + t];
            int   ix = ri[tid * 33 + t];
            if (sv < best || (sv == best && ix < bidx)) { best = sv; bidx = ix; }
        }
        // score > 0 always (||z||^2 ~ 256 dominates) -> fp32 bits order-preserving
        unsigned long long key =
            ((unsigned long long)__float_as_uint(best) << 32) | (unsigned)bidx;
        atomicMin(keyp + tid, key);
    }
    __threadfence();
    __syncthreads();
    if (tid == 0) sflag = atomicAdd(cnt + p, 1);
    __syncthreads();
    if (sflag == SPLIT - 1) {         // last split: gather + store 64 pixels
        if (tid < MT) {
            unsigned long long v = atomicMin(keyp + tid, 0xFFFFFFFFFFFFFFFFull);
            idxs[tid] = (int)(unsigned)v;
        }
        __syncthreads();
        float* obase = out + (size_t)b * (D_ * HW_) + hwbase;
        #pragma unroll
        for (int it = 0; it < 16; ++it) {
            int uu = (it << 8) + tid;
            int dd = uu >> 4;         // [0,256)
            int c4 = uu & 15;         // float4 column among 64 pixels
            int i0 = idxs[(c4 << 2) + 0];
            int i1 = idxs[(c4 << 2) + 1];
            int i2 = idxs[(c4 << 2) + 2];
            int i3 = idxs[(c4 << 2) + 3];
            float4 o;
            o.x = cb[(size_t)i0 * D_ + dd];
            o.y = cb[(size_t)i1 * D_ + dd];
            o.z = cb[(size_t)i2 * D_ + dd];
            o.w = cb[(size_t)i3 * D_ + dd];
            *reinterpret_cast<float4*>(obase + (size_t)dd * HW_ + (c4 << 2)) = o;
        }
    }
}

extern "C" void kernel_launch(void* const* d_in, const int* in_sizes, int n_in,
                              void* d_out, int out_size, void* d_ws, size_t ws_size,
                              hipStream_t stream) {
    const float* z  = (const float*)d_in[0];   // 16*256*32*32
    const float* cb = (const float*)d_in[1];   // 2048*256
    unsigned long long* keys = (unsigned long long*)d_ws;   // 16384
    int*   cnt = (int*)(keys + NPIX);                       // 256
    float* An  = (float*)(cnt + 256);                       // 16384
    float* Bn  = An + NPIX;                                 // 2048
    float* ct  = Bn + K_;                                   // 256*2048 (2 MB)
    float* out = (float*)d_out;

    prep_k<<<dim3(200), dim3(256), 0, stream>>>(z, cb, ct, An, Bn, keys, cnt);
    vq_k<<<dim3(256 * SPLIT), dim3(256), 0, stream>>>(z, ct, cb, An, Bn,
                                                      keys, cnt, out);
}